// Round 18
// baseline (344.531 us; speedup 1.0000x reference)
//
#include <hip/hip_runtime.h>

#define NFEAT 256
#define BN_EPSF 1e-5f
#define CH_J 256            // j's per pooled-GEMM chunk (must be multiple of 64)
#define ELLW 96             // ELL width; in/out-degree ~ Poisson(32), P(>=96) ~ 0
#define BSH 7               // bucket = node >> 7 (128 nodes/bucket)
#define PBKT 392            // buckets (covers N_pad = 50176 = 392*128)
#define PCAP 4608           // per-bucket edge capacity (mean 4082, +8 sigma)
#define PEDG 4992           // edges per partition block (LDS-cached chunk)
#define CT_SCALE 64.0f      // Ct prescale so fp8 hi/lo stays in e4m3 normal range

typedef __attribute__((ext_vector_type(8))) short bf16x8;
typedef __attribute__((ext_vector_type(4))) float f32x4;
typedef __attribute__((ext_vector_type(2))) float f32x2;

__device__ __forceinline__ unsigned short f2bf(float f) {
    union { float f; unsigned u; } v; v.f = f;
    unsigned r = v.u + 0x7fffu + ((v.u >> 16) & 1u);  // round-to-nearest-even
    return (unsigned short)(r >> 16);
}
__device__ __forceinline__ float bf2f(unsigned short h) {
    union { unsigned u; float f; } v; v.u = ((unsigned)h) << 16;
    return v.f;
}

// ---------------- graph preprocessing: partition-based (coalesced) build ----------------

__global__ __launch_bounds__(256) void k_part(const int* __restrict__ src, const int* __restrict__ dst,
                                              int* __restrict__ curD, int* __restrict__ curS,
                                              unsigned* __restrict__ partD, unsigned* __restrict__ partS, int E) {
    __shared__ int cD[PBKT], cS[PBKT], bD[PBKT], bS[PBKT];
    __shared__ int2 eds[PEDG];   // 40KB edge cache
    for (int t = threadIdx.x; t < PBKT; t += 256) { cD[t] = 0; cS[t] = 0; }
    __syncthreads();
    int e0 = blockIdx.x * PEDG;
    int ne = min(E - e0, PEDG);
    for (int i = threadIdx.x; i < ne; i += 256) {
        int2 e; e.x = src[e0 + i]; e.y = dst[e0 + i];
        eds[i] = e;
        atomicAdd(&cD[e.y >> BSH], 1);
        atomicAdd(&cS[e.x >> BSH], 1);
    }
    __syncthreads();
    for (int t = threadIdx.x; t < PBKT; t += 256) {
        bD[t] = cD[t] ? atomicAdd(&curD[t], cD[t]) : 0;
        bS[t] = cS[t] ? atomicAdd(&curS[t], cS[t]) : 0;
        cD[t] = 0; cS[t] = 0;
    }
    __syncthreads();
    for (int i = threadIdx.x; i < ne; i += 256) {
        int2 e = eds[i];
        int b1 = e.y >> BSH;
        int p1 = bD[b1] + atomicAdd(&cD[b1], 1);
        if (p1 < PCAP) partD[(size_t)b1 * PCAP + p1] = ((unsigned)(e.y & 127) << 16) | (unsigned)e.x;
        int b2 = e.x >> BSH;
        int p2 = bS[b2] + atomicAdd(&cS[b2], 1);
        if (p2 < PCAP) partS[(size_t)b2 * PCAP + p2] = ((unsigned)(e.x & 127) << 16) | (unsigned)e.y;
    }
}

// merged prep: blocks [0,256) transpose W1 to bf16; blocks >= 256 repack x to float4
__global__ __launch_bounds__(256) void k_prep(const float* __restrict__ W, unsigned short* __restrict__ Wt,
                                              const float* __restrict__ x, float4* __restrict__ x4, int N) {
    if (blockIdx.x < 256) {
        int k = blockIdx.x, n = threadIdx.x;
        Wt[n * 256 + k] = f2bf(W[k * 256 + n]);
    } else {
        int i = (blockIdx.x - 256) * 256 + threadIdx.x;
        if (i < N) {
            float4 r; r.x = x[i * 3 + 0]; r.y = x[i * 3 + 1]; r.z = x[i * 3 + 2]; r.w = 0.f;
            x4[i] = r;
        }
    }
}

// Phase 2: one block per dst-bucket; 128 ELL rows in LDS, coalesced ushort write.
__global__ __launch_bounds__(256) void k_buildIn(const unsigned* __restrict__ partD, const int* __restrict__ curD,
                                                 const int* __restrict__ batch,
                                                 unsigned short* __restrict__ ell_in, int* __restrict__ cnt,
                                                 float* __restrict__ dinv, float2* __restrict__ pack, int N) {
    __shared__ int rows[128][ELLW];   // 49KB
    __shared__ int cur[128];
    int b = blockIdx.x;
    if (threadIdx.x < 128) cur[threadIdx.x] = 0;
    __syncthreads();
    int lo = b << BSH;
    int ne = min(curD[b], PCAP);
    const unsigned* seg = partD + (size_t)b * PCAP;
    for (int i = threadIdx.x; i < ne; i += 256) {
        unsigned u = seg[i];
        int r = u >> 16;
        int pos = atomicAdd(&cur[r], 1);
        if (pos < ELLW) rows[r][pos] = (int)(u & 0xFFFFu);
    }
    __syncthreads();
    const int Q = ELLW / 8;           // 12 chunks of 8 ushorts (16B) per row
    for (int idx = threadIdx.x; idx < 128 * Q; idx += 256) {
        int r = idx / Q, q = idx % Q;
        if (lo + r < N) {
            unsigned short tmp[8];
#pragma unroll
            for (int j = 0; j < 8; j++) tmp[j] = (unsigned short)rows[r][q * 8 + j];
            *(uint4*)(ell_in + (size_t)(lo + r) * ELLW + q * 8) = *(const uint4*)tmp;
        }
    }
    if (threadIdx.x < 128) {
        int node = lo + threadIdx.x;
        if (node < N) {
            int c = cur[threadIdx.x];
            cnt[node] = c;
            float d = rsqrtf((float)(min(c, ELLW) + 1));  // +1 self-loop
            dinv[node] = d;
            float2 pk; pk.x = d; pk.y = __int_as_float(batch[node]);
            pack[node] = pk;
        }
    }
}

// Phase 3: one block per src-bucket; Ct rows in LDS, transposed fp8 hi/lo out (x64 scale).
__global__ __launch_bounds__(256) void k_buildCt(const unsigned* __restrict__ partS, const int* __restrict__ curS,
                                                 const float2* __restrict__ pack,
                                                 unsigned char* __restrict__ ct_hi,
                                                 unsigned char* __restrict__ ct_lo,
                                                 int N, int N_pad) {
    __shared__ float ct[128][65];   // +1 pad kills bank conflicts in transpose read
    __shared__ float dv[128];
    int b = blockIdx.x;
    for (int idx = threadIdx.x; idx < 128 * 65; idx += 256) (&ct[0][0])[idx] = 0.f;
    __syncthreads();
    int lo = b << BSH;
    int ne = min(curS[b], PCAP);
    const unsigned* seg = partS + (size_t)b * PCAP;
    for (int i = threadIdx.x; i < ne; i += 256) {
        unsigned u = seg[i];
        float2 pk = pack[u & 0xFFFFu];
        atomicAdd(&ct[u >> 16][__float_as_int(pk.y)], pk.x);
    }
    __syncthreads();
    if (threadIdx.x < 128) {
        int node = lo + threadIdx.x;
        if (node < N) {
            float2 ps = pack[node];
            dv[threadIdx.x] = ps.x;
            ct[threadIdx.x][__float_as_int(ps.y)] += ps.x;   // self-loop (exclusive row owner)
        } else dv[threadIdx.x] = 0.f;
    }
    __syncthreads();
    int g = threadIdx.x >> 2, js = (threadIdx.x & 3) * 32;
    unsigned char hv[32], lv[32];
#pragma unroll
    for (int p = 0; p < 16; p++) {
        float v0 = dv[js + 2 * p] * ct[js + 2 * p][g] * CT_SCALE;
        float v1 = dv[js + 2 * p + 1] * ct[js + 2 * p + 1][g] * CT_SCALE;
        int ph = __builtin_amdgcn_cvt_pk_fp8_f32(v0, v1, 0, false);
        f32x2 dec = __builtin_amdgcn_cvt_pk_f32_fp8(ph, false);
        int pl = __builtin_amdgcn_cvt_pk_fp8_f32(v0 - dec[0], v1 - dec[1], 0, false);
        hv[2 * p] = (unsigned char)(ph & 0xff);
        hv[2 * p + 1] = (unsigned char)((ph >> 8) & 0xff);
        lv[2 * p] = (unsigned char)(pl & 0xff);
        lv[2 * p + 1] = (unsigned char)((pl >> 8) & 0xff);
    }
    size_t basep = (size_t)g * N_pad + lo + js;
    *(uint4*)(ct_hi + basep) = *(const uint4*)&hv[0];
    *(uint4*)(ct_hi + basep + 16) = *(const uint4*)&hv[16];
    *(uint4*)(ct_lo + basep) = *(const uint4*)&lv[0];
    *(uint4*)(ct_lo + basep + 16) = *(const uint4*)&lv[16];
}

// ---------------- layer 0 fused: wave-per-node gather + 3->256 matmul + BN + ReLU ----------------
// Also zero-fills bf16 pad rows [N, N_pad) (replaces a memset).

__global__ __launch_bounds__(256) void k_l0(const float4* __restrict__ x4, const unsigned short* __restrict__ ell_in,
                                            const int* __restrict__ cnt, const float* __restrict__ dinv,
                                            const float* __restrict__ W, const float* __restrict__ b,
                                            const float* __restrict__ g, const float* __restrict__ be,
                                            const float* __restrict__ m, const float* __restrict__ v,
                                            unsigned short* __restrict__ h, int N) {
    int wv = threadIdx.x >> 6, lane = threadIdx.x & 63;
    int node = blockIdx.x * 4 + wv;
    int c4 = lane * 4;
    if (node >= N) {
        ushort4 z = {0, 0, 0, 0};
        *(ushort4*)(h + (size_t)node * NFEAT + c4) = z;
        return;
    }
    float dvn = dinv[node];
    int len = min(cnt[node], ELLW);
    const unsigned short* nb = ell_in + (size_t)node * ELLW;
    float a0 = 0.f, a1 = 0.f, a2 = 0.f;
    for (int e = lane; e < len; e += 64) {
        int s = nb[e];
        float4 xv = x4[s];                 // single dwordx4 gather
        float w = dinv[s] * dvn;
        a0 += w * xv.x;
        a1 += w * xv.y;
        a2 += w * xv.z;
    }
#pragma unroll
    for (int off = 32; off; off >>= 1) {
        a0 += __shfl_xor(a0, off);
        a1 += __shfl_xor(a1, off);
        a2 += __shfl_xor(a2, off);
    }
    float4 xs = x4[node];
    float wself = dvn * dvn;   // identical in all lanes
    a0 += wself * xs.x;
    a1 += wself * xs.y;
    a2 += wself * xs.z;
    float4 w0 = *(const float4*)(W + c4);
    float4 w1 = *(const float4*)(W + NFEAT + c4);
    float4 w2 = *(const float4*)(W + 2 * NFEAT + c4);
    float4 bb = *(const float4*)(b + c4);
    float4 gg = *(const float4*)(g + c4);
    float4 ee = *(const float4*)(be + c4);
    float4 mm = *(const float4*)(m + c4);
    float4 vv = *(const float4*)(v + c4);
    float r0 = ((a0 * w0.x + a1 * w1.x + a2 * w2.x) + bb.x - mm.x) * rsqrtf(vv.x + BN_EPSF) * gg.x + ee.x;
    float r1 = ((a0 * w0.y + a1 * w1.y + a2 * w2.y) + bb.y - mm.y) * rsqrtf(vv.y + BN_EPSF) * gg.y + ee.y;
    float r2 = ((a0 * w0.z + a1 * w1.z + a2 * w2.z) + bb.z - mm.z) * rsqrtf(vv.z + BN_EPSF) * gg.z + ee.z;
    float r3 = ((a0 * w0.w + a1 * w1.w + a2 * w2.w) + bb.w - mm.w) * rsqrtf(vv.w + BN_EPSF) * gg.w + ee.w;
    ushort4 o;
    o.x = f2bf(fmaxf(r0, 0.f)); o.y = f2bf(fmaxf(r1, 0.f));
    o.z = f2bf(fmaxf(r2, 0.f)); o.w = f2bf(fmaxf(r3, 0.f));
    *(ushort4*)(h + (size_t)node * NFEAT + c4) = o;
}

// ---------------- bf16 MFMA GEMM -> fp8 e4m3 output: C8[M][256] bytes ----------------

__global__ __launch_bounds__(256) void k_mm_mfma(const unsigned short* __restrict__ A,
                                                 const unsigned short* __restrict__ Bt,
                                                 unsigned char* __restrict__ C8) {
    __shared__ __align__(16) unsigned short As[4][128][8];  // [kchunk][row][j] 8KB
    __shared__ __align__(16) unsigned short Bs[4][128][8];  // [kchunk][col][j] 8KB
    int bm = blockIdx.x * 128, bn = blockIdx.y * 128;
    int tid = threadIdx.x;
    int lane = tid & 63, wave = tid >> 6;
    int wm = (wave & 1) * 64, wn = (wave >> 1) * 64;
    int lrow = lane & 15, lk = lane >> 4;
    f32x4 acc[4][4] = {};

    for (int k0 = 0; k0 < 256; k0 += 32) {
#pragma unroll
        for (int i = 0; i < 2; i++) {
            int idx = tid + 256 * i;
            int ch = idx & 3, row = idx >> 2;
            *(uint4*)(&As[ch][row][0]) = *(const uint4*)(A + (size_t)(bm + row) * 256 + k0 + ch * 8);
            *(uint4*)(&Bs[ch][row][0]) = *(const uint4*)(Bt + (size_t)(bn + row) * 256 + k0 + ch * 8);
        }
        __syncthreads();
        bf16x8 af[4], bf[4];
#pragma unroll
        for (int r = 0; r < 4; r++) af[r] = *(const bf16x8*)(&As[lk][wm + r * 16 + lrow][0]);
#pragma unroll
        for (int c = 0; c < 4; c++) bf[c] = *(const bf16x8*)(&Bs[lk][wn + c * 16 + lrow][0]);
#pragma unroll
        for (int r = 0; r < 4; r++)
#pragma unroll
            for (int c = 0; c < 4; c++)
                acc[r][c] = __builtin_amdgcn_mfma_f32_16x16x32_bf16(af[r], bf[c], acc[r][c], 0, 0, 0);
        __syncthreads();
    }

#pragma unroll
    for (int r = 0; r < 4; r++) {
#pragma unroll
        for (int reg = 0; reg < 4; reg++) {
            int grow = bm + wm + r * 16 + lk * 4 + reg;
            int p01 = __builtin_amdgcn_cvt_pk_fp8_f32(acc[r][0][reg], acc[r][1][reg], 0, false);
            int p23 = __builtin_amdgcn_cvt_pk_fp8_f32(acc[r][2][reg], acc[r][3][reg], 0, false);
            size_t base = (size_t)grow * 256 + bn + wn + lrow;
            C8[base]      = (unsigned char)(p01 & 0xff);
            C8[base + 16] = (unsigned char)((p01 >> 8) & 0xff);
            C8[base + 32] = (unsigned char)(p23 & 0xff);
            C8[base + 48] = (unsigned char)((p23 >> 8) & 0xff);
        }
    }
}

// ---------------- fp8 aggregation with fused BN affine + ReLU (layer 1) ----------------
// Output A1 stored fp8 (consumed only by the pooled GEMM; pooling averages the noise).
// Grid covers N_pad; pad nodes write zero rows.

template <bool RELU>
__global__ __launch_bounds__(64) void k_agg256b(const unsigned char* __restrict__ t,
                                                const unsigned short* __restrict__ ell_in,
                                                const int* __restrict__ cnt,
                                                const float* __restrict__ dinv,
                                                const float* __restrict__ b, const float* __restrict__ g,
                                                const float* __restrict__ be, const float* __restrict__ m,
                                                const float* __restrict__ v, unsigned char* __restrict__ out, int N) {
    __shared__ int s_idx[64];
    __shared__ float s_w[64];
    int node = blockIdx.x;
    int c4 = threadIdx.x * 4;
    if (node >= N) {
        *(unsigned*)(out + (size_t)node * NFEAT + c4) = 0u;
        return;
    }
    float dv = dinv[node];
    float a0, a1, a2, a3;
    {
        unsigned u = *(const unsigned*)(t + (size_t)node * NFEAT + c4);
        f32x2 flo = __builtin_amdgcn_cvt_pk_f32_fp8(u, false);
        f32x2 fhi = __builtin_amdgcn_cvt_pk_f32_fp8(u, true);
        float w = dv * dv;
        a0 = w * flo[0]; a1 = w * flo[1]; a2 = w * fhi[0]; a3 = w * fhi[1];
    }
    int len = min(cnt[node], ELLW);
    const unsigned short* nb = ell_in + (size_t)node * ELLW;
    for (int base = 0; base < len; base += 64) {
        int chunk = min(64, len - base);
        if ((int)threadIdx.x < chunk) {
            int s = nb[base + threadIdx.x];
            s_idx[threadIdx.x] = s;
            s_w[threadIdx.x] = dinv[s] * dv;
        }
        __syncthreads();
        int j = 0;
        for (; j + 4 <= chunk; j += 4) {
            unsigned u0 = *(const unsigned*)(t + (size_t)s_idx[j + 0] * NFEAT + c4);
            unsigned u1 = *(const unsigned*)(t + (size_t)s_idx[j + 1] * NFEAT + c4);
            unsigned u2 = *(const unsigned*)(t + (size_t)s_idx[j + 2] * NFEAT + c4);
            unsigned u3 = *(const unsigned*)(t + (size_t)s_idx[j + 3] * NFEAT + c4);
            float w0 = s_w[j + 0], w1 = s_w[j + 1], w2 = s_w[j + 2], w3 = s_w[j + 3];
            f32x2 l0 = __builtin_amdgcn_cvt_pk_f32_fp8(u0, false), h0 = __builtin_amdgcn_cvt_pk_f32_fp8(u0, true);
            f32x2 l1 = __builtin_amdgcn_cvt_pk_f32_fp8(u1, false), h1 = __builtin_amdgcn_cvt_pk_f32_fp8(u1, true);
            f32x2 l2 = __builtin_amdgcn_cvt_pk_f32_fp8(u2, false), h2 = __builtin_amdgcn_cvt_pk_f32_fp8(u2, true);
            f32x2 l3 = __builtin_amdgcn_cvt_pk_f32_fp8(u3, false), h3 = __builtin_amdgcn_cvt_pk_f32_fp8(u3, true);
            a0 += w0 * l0[0]; a1 += w0 * l0[1]; a2 += w0 * h0[0]; a3 += w0 * h0[1];
            a0 += w1 * l1[0]; a1 += w1 * l1[1]; a2 += w1 * h1[0]; a3 += w1 * h1[1];
            a0 += w2 * l2[0]; a1 += w2 * l2[1]; a2 += w2 * h2[0]; a3 += w2 * h2[1];
            a0 += w3 * l3[0]; a1 += w3 * l3[1]; a2 += w3 * h3[0]; a3 += w3 * h3[1];
        }
        for (; j < chunk; j++) {
            unsigned u = *(const unsigned*)(t + (size_t)s_idx[j] * NFEAT + c4);
            float w = s_w[j];
            f32x2 flo = __builtin_amdgcn_cvt_pk_f32_fp8(u, false);
            f32x2 fhi = __builtin_amdgcn_cvt_pk_f32_fp8(u, true);
            a0 += w * flo[0]; a1 += w * flo[1]; a2 += w * fhi[0]; a3 += w * fhi[1];
        }
        __syncthreads();
    }
    float4 bb = *(const float4*)(b + c4);
    float4 gg = *(const float4*)(g + c4);
    float4 ee = *(const float4*)(be + c4);
    float4 mm = *(const float4*)(m + c4);
    float4 vv = *(const float4*)(v + c4);
    float r0 = (a0 + bb.x - mm.x) * rsqrtf(vv.x + BN_EPSF) * gg.x + ee.x;
    float r1 = (a1 + bb.y - mm.y) * rsqrtf(vv.y + BN_EPSF) * gg.y + ee.y;
    float r2 = (a2 + bb.z - mm.z) * rsqrtf(vv.z + BN_EPSF) * gg.z + ee.z;
    float r3 = (a3 + bb.w - mm.w) * rsqrtf(vv.w + BN_EPSF) * gg.w + ee.w;
    if (RELU) { r0 = fmaxf(r0, 0.f); r1 = fmaxf(r1, 0.f); r2 = fmaxf(r2, 0.f); r3 = fmaxf(r3, 0.f); }
    int p01 = __builtin_amdgcn_cvt_pk_fp8_f32(r0, r1, 0, false);
    int p23 = __builtin_amdgcn_cvt_pk_fp8_f32(r2, r3, 0, false);
    unsigned pk = (unsigned)(p01 & 0xffff) | ((unsigned)(p23 & 0xffff) << 16);
    *(unsigned*)(out + (size_t)node * NFEAT + c4) = pk;
}

// ---------------- pooled GEMM via fp8 MFMA: P[ch][c][g] = sum_j A1[j][c]*Ct[j][g] ----------------
// A = A1 fp8 (8 strided byte gathers packed to i64); B = CtT fp8 hi/lo (x64 scaled).

__global__ __launch_bounds__(256) void k_cgemm(const unsigned char* __restrict__ A1,
                                               const unsigned char* __restrict__ ct_hi,
                                               const unsigned char* __restrict__ ct_lo,
                                               float* __restrict__ P, int N_pad) {
    __shared__ __align__(16) unsigned char s_hi[64 * 40];  // [g][j] 32B data, stride 40
    __shared__ __align__(16) unsigned char s_lo[64 * 40];
    int tid = threadIdx.x;
    int lane = tid & 63, wv = tid >> 6;
    int lc = lane & 15, q = lane >> 4;
    int cbase = blockIdx.y * 64 + wv * 16;
    int j0 = blockIdx.x * CH_J;
    int sg = tid >> 2, sj8 = (tid & 3) * 8;  // staging: 64 g x 32 j, 8B per thread
    f32x4 acc[4] = {};

    for (int ks = 0; ks < CH_J; ks += 32) {
        size_t cbs = (size_t)sg * N_pad + j0 + ks + sj8;
        *(uint2*)(&s_hi[sg * 40 + sj8]) = *(const uint2*)(ct_hi + cbs);
        *(uint2*)(&s_lo[sg * 40 + sj8]) = *(const uint2*)(ct_lo + cbs);
        __syncthreads();
        const unsigned char* ap = A1 + (size_t)(j0 + ks + q * 8) * 256 + cbase + lc;
        unsigned long long a = 0;
#pragma unroll
        for (int jj = 0; jj < 8; jj++) a |= (unsigned long long)ap[(size_t)jj * 256] << (8 * jj);
#pragma unroll
        for (int nt = 0; nt < 4; nt++) {
            unsigned long long bh = *(const unsigned long long*)(&s_hi[(nt * 16 + lc) * 40 + q * 8]);
            unsigned long long bl = *(const unsigned long long*)(&s_lo[(nt * 16 + lc) * 40 + q * 8]);
            acc[nt] = __builtin_amdgcn_mfma_f32_16x16x32_fp8_fp8((long)a, (long)bh, acc[nt], 0, 0, 0);
            acc[nt] = __builtin_amdgcn_mfma_f32_16x16x32_fp8_fp8((long)a, (long)bl, acc[nt], 0, 0, 0);
        }
        __syncthreads();
    }
    // D: m(c) = q*4+reg, n(g) = nt*16+lc; store P[ch][c][g]
    float* pp = P + (size_t)blockIdx.x * 64 * 256;
#pragma unroll
    for (int nt = 0; nt < 4; nt++) {
        int g = nt * 16 + lc;
#pragma unroll
        for (int reg = 0; reg < 4; reg++) {
            int c = cbase + q * 4 + reg;
            pp[(size_t)c * 64 + g] = acc[nt][reg];
        }
    }
}

// reduce partials over chunks: pooled[g][c] = sum_ch P[ch][c][g]; 256 blocks (one per c)
__global__ __launch_bounds__(64) void k_redP(const float* __restrict__ P,
                                             float* __restrict__ pooled, int nch) {
    int c = blockIdx.x;
    int g = threadIdx.x;
    float acc = 0.f;
    const float* pp = P + (size_t)c * 64 + g;
    for (int ch = 0; ch < nch; ch++) acc += pp[(size_t)ch * 64 * 256];
    pooled[(size_t)g * 256 + c] = acc;
}

// W2 mini-GEMM + mean + bias + BN -> d_out (CT_SCALE folded into the mean)
__global__ __launch_bounds__(256) void k_out(const float* __restrict__ pooled,
                                             const float* __restrict__ W2,
                                             const int* __restrict__ batch,
                                             const float* __restrict__ b, const float* __restrict__ gw,
                                             const float* __restrict__ be, const float* __restrict__ m,
                                             const float* __restrict__ v,
                                             float* __restrict__ out, int N) {
    __shared__ float s_pool[256];
    __shared__ int s_cnt;
    int g = blockIdx.x;
    int c = threadIdx.x;
    s_pool[c] = pooled[(size_t)g * 256 + c];
    if (threadIdx.x == 0) {
        int lo = 0, hi = N;
        while (lo < hi) { int mid = (lo + hi) >> 1; if (batch[mid] < g) lo = mid + 1; else hi = mid; }
        int st = lo;
        lo = 0; hi = N;
        while (lo < hi) { int mid = (lo + hi) >> 1; if (batch[mid] < g + 1) lo = mid + 1; else hi = mid; }
        s_cnt = lo - st;
    }
    __syncthreads();
    float dot = 0.f;
    for (int k = 0; k < 256; k += 4) {
        float4 pk = *(const float4*)(s_pool + k);
        dot += pk.x * W2[(k + 0) * 256 + c];
        dot += pk.y * W2[(k + 1) * 256 + c];
        dot += pk.z * W2[(k + 2) * 256 + c];
        dot += pk.w * W2[(k + 3) * 256 + c];
    }
    float r = 0.f;
    int cntg = s_cnt;
    if (cntg > 0) {
        float mean = dot / (CT_SCALE * (float)cntg) + b[c];
        r = (mean - m[c]) * rsqrtf(v[c] + BN_EPSF) * gw[c] + be[c];
    }
    out[g * 256 + c] = r;
}

// ---------------- launch ----------------

static inline size_t align_up(size_t x, size_t a) { return (x + a - 1) & ~(a - 1); }

extern "C" void kernel_launch(void* const* d_in, const int* in_sizes, int n_in,
                              void* d_out, int out_size, void* d_ws, size_t ws_size,
                              hipStream_t stream) {
    const float* x = (const float*)d_in[0];
    const int* edge_index = (const int*)d_in[1];
    const int* batch = (const int*)d_in[2];

    const int N = in_sizes[2];          // 50000 (< 2^16, required by u32/u16 packing)
    const int E = in_sizes[1] / 2;      // 1600000
    const int NCH = (N + CH_J - 1) / CH_J;   // pooled-GEMM chunks (196)
    const int N_pad = NCH * CH_J;            // 50176 = PBKT*128

    const int* e_src = edge_index;
    const int* e_dst = edge_index + E;

    const float* W[3]; const float* bP[3]; const float* gP[3];
    const float* beP[3]; const float* mP[3]; const float* vP[3];
    for (int i = 0; i < 3; i++) {
        W[i]  = (const float*)d_in[3 + 6 * i + 0];
        bP[i] = (const float*)d_in[3 + 6 * i + 1];
        gP[i] = (const float*)d_in[3 + 6 * i + 2];
        beP[i]= (const float*)d_in[3 + 6 * i + 3];
        mP[i] = (const float*)d_in[3 + 6 * i + 4];
        vP[i] = (const float*)d_in[3 + 6 * i + 5];
    }

    // workspace carve-up
    char* ws = (char*)d_ws;
    size_t off = 0;
    auto carve = [&](size_t bytes) { void* p = ws + off; off = align_up(off + bytes, 256); return p; };
    int*   curD     = (int*)  carve((size_t)2 * PBKT * 4);   // bucket cursors, one memset
    int*   curS     = curD + PBKT;
    int*   cnt      = (int*)  carve((size_t)N * 4);
    float* dinv     = (float*)carve((size_t)N * 4);
    float2* pack    = (float2*)carve((size_t)N * 8);
    float4* x4      = (float4*)carve((size_t)N * 16);
    unsigned* partD = (unsigned*)carve((size_t)PBKT * PCAP * 4);  // 7.2 MB (packed u32)
    unsigned* partS = (unsigned*)carve((size_t)PBKT * PCAP * 4);  // 7.2 MB
    unsigned short* ell_in = (unsigned short*)carve((size_t)N * ELLW * 2);  // 9.6 MB (u16)
    unsigned short* bufA = (unsigned short*)carve((size_t)N_pad * NFEAT * 2);  // A0 bf16
    unsigned char*  bufY = (unsigned char*)carve((size_t)N_pad * NFEAT);    // fp8 Y (12.8 MB)
    unsigned char*  bufA1 = (unsigned char*)carve((size_t)N_pad * NFEAT);   // fp8 A1 (12.8 MB)
    unsigned short* Wt1  = (unsigned short*)carve((size_t)NFEAT * NFEAT * 2);
    unsigned char*  ct_hi = (unsigned char*)carve((size_t)N_pad * 64);      // fp8 (3.2 MB)
    unsigned char*  ct_lo = (unsigned char*)carve((size_t)N_pad * 64);
    float* partials = (float*)carve((size_t)NCH * 64 * 256 * 4);     // 12.85 MB
    float* pooled   = (float*)carve((size_t)64 * 256 * 4);
    (void)ws_size;

    hipMemsetAsync(curD, 0, (size_t)2 * PBKT * 4, stream);

    const int BS = 256;
    // phase 1: partition edges (packed u32 entries; LDS-cached chunk)
    k_part<<<(E + PEDG - 1) / PEDG, BS, 0, stream>>>(e_src, e_dst, curD, curS, partD, partS, E);
    // merged prep: W1 transpose (256 blocks) + x float4 repack
    k_prep<<<256 + (N + BS - 1) / BS, BS, 0, stream>>>(W[1], Wt1, x, x4, N);
    // phase 2: ELL rows in LDS -> coalesced u16 write; cnt/dinv/pack fall out
    k_buildIn<<<PBKT, BS, 0, stream>>>(partD, curD, batch, ell_in, cnt, dinv, pack, N);
    // phase 3: Ct rows in LDS -> transposed fp8 hi/lo (x64) directly
    k_buildCt<<<PBKT, BS, 0, stream>>>(partS, curS, pack, ct_hi, ct_lo, N, N_pad);

    // layer 0 fused: gather-aggregate (float4 x) + 3->256 matmul + BN + ReLU -> bf16 (+pad zero)
    k_l0<<<N_pad / 4, BS, 0, stream>>>(x4, ell_in, cnt, dinv, W[0],
                                       bP[0], gP[0], beP[0], mP[0], vP[0], bufA, N);

    dim3 mmGrid((N + 127) / 128, 2);
    // layer 1: Y = h@W1 (MFMA, fp8 out) -> propagate (fp8 gather) -> BN + ReLU -> fp8 A1
    k_mm_mfma<<<mmGrid, 256, 0, stream>>>(bufA, Wt1, bufY);
    k_agg256b<true><<<N_pad, 64, 0, stream>>>(bufY, ell_in, cnt, dinv,
                                              bP[1], gP[1], beP[1], mP[1], vP[1], bufA1, N);

    // layer 2 + pool (W2 folded out): P = per-chunk Ct^T @ A1 via fp8 MFMA; out = BN((P@W2)/(64n) + b2)
    dim3 cgGrid(NCH, 4);
    k_cgemm<<<cgGrid, 256, 0, stream>>>(bufA1, ct_hi, ct_lo, partials, N_pad);
    k_redP<<<256, 64, 0, stream>>>(partials, pooled, NCH);
    k_out<<<64, 256, 0, stream>>>(pooled, W[2], batch, bP[2], gP[2], beP[2], mP[2], vP[2],
                                  (float*)d_out, N);
}

// Round 19
// 329.496 us; speedup vs baseline: 1.0456x; 1.0456x over previous
//
#include <hip/hip_runtime.h>

#define NFEAT 256
#define BN_EPSF 1e-5f
#define CH_J 512            // j's per pooled-GEMM chunk (must be multiple of 64)
#define ELLW 96             // ELL width; in/out-degree ~ Poisson(32), P(>=96) ~ 0
#define BSH 7               // bucket = node >> 7 (128 nodes/bucket)
#define PBKT 392            // buckets (covers N_pad = 50176 = 392*128)
#define PCAP 4608           // per-bucket edge capacity (mean 4082, +8 sigma)
#define PEDG 4992           // edges per partition block (LDS-cached chunk)

typedef __attribute__((ext_vector_type(8))) short bf16x8;
typedef __attribute__((ext_vector_type(4))) float f32x4;
typedef __attribute__((ext_vector_type(2))) float f32x2;

__device__ __forceinline__ unsigned short f2bf(float f) {
    union { float f; unsigned u; } v; v.f = f;
    unsigned r = v.u + 0x7fffu + ((v.u >> 16) & 1u);  // round-to-nearest-even
    return (unsigned short)(r >> 16);
}
__device__ __forceinline__ float bf2f(unsigned short h) {
    union { unsigned u; float f; } v; v.u = ((unsigned)h) << 16;
    return v.f;
}

// ---------------- graph preprocessing: partition-based (coalesced) build ----------------

__global__ __launch_bounds__(256) void k_part(const int* __restrict__ src, const int* __restrict__ dst,
                                              int* __restrict__ curD, int* __restrict__ curS,
                                              unsigned* __restrict__ partD, unsigned* __restrict__ partS, int E) {
    __shared__ int cD[PBKT], cS[PBKT], bD[PBKT], bS[PBKT];
    __shared__ int2 eds[PEDG];   // 40KB edge cache
    for (int t = threadIdx.x; t < PBKT; t += 256) { cD[t] = 0; cS[t] = 0; }
    __syncthreads();
    int e0 = blockIdx.x * PEDG;
    int ne = min(E - e0, PEDG);
    for (int i = threadIdx.x; i < ne; i += 256) {
        int2 e; e.x = src[e0 + i]; e.y = dst[e0 + i];
        eds[i] = e;
        atomicAdd(&cD[e.y >> BSH], 1);
        atomicAdd(&cS[e.x >> BSH], 1);
    }
    __syncthreads();
    for (int t = threadIdx.x; t < PBKT; t += 256) {
        bD[t] = cD[t] ? atomicAdd(&curD[t], cD[t]) : 0;
        bS[t] = cS[t] ? atomicAdd(&curS[t], cS[t]) : 0;
        cD[t] = 0; cS[t] = 0;
    }
    __syncthreads();
    for (int i = threadIdx.x; i < ne; i += 256) {
        int2 e = eds[i];
        int b1 = e.y >> BSH;
        int p1 = bD[b1] + atomicAdd(&cD[b1], 1);
        if (p1 < PCAP) partD[(size_t)b1 * PCAP + p1] = ((unsigned)(e.y & 127) << 16) | (unsigned)e.x;
        int b2 = e.x >> BSH;
        int p2 = bS[b2] + atomicAdd(&cS[b2], 1);
        if (p2 < PCAP) partS[(size_t)b2 * PCAP + p2] = ((unsigned)(e.x & 127) << 16) | (unsigned)e.y;
    }
}

// merged prep: blocks [0,256) transpose W1 to bf16; blocks >= 256 repack x to float4
__global__ __launch_bounds__(256) void k_prep(const float* __restrict__ W, unsigned short* __restrict__ Wt,
                                              const float* __restrict__ x, float4* __restrict__ x4, int N) {
    if (blockIdx.x < 256) {
        int k = blockIdx.x, n = threadIdx.x;
        Wt[n * 256 + k] = f2bf(W[k * 256 + n]);
    } else {
        int i = (blockIdx.x - 256) * 256 + threadIdx.x;
        if (i < N) {
            float4 r; r.x = x[i * 3 + 0]; r.y = x[i * 3 + 1]; r.z = x[i * 3 + 2]; r.w = 0.f;
            x4[i] = r;
        }
    }
}

// Phase 2: one block per dst-bucket; 128 ELL rows in LDS, coalesced ushort write.
__global__ __launch_bounds__(256) void k_buildIn(const unsigned* __restrict__ partD, const int* __restrict__ curD,
                                                 const int* __restrict__ batch,
                                                 unsigned short* __restrict__ ell_in, int* __restrict__ cnt,
                                                 float* __restrict__ dinv, float2* __restrict__ pack, int N) {
    __shared__ int rows[128][ELLW];   // 49KB
    __shared__ int cur[128];
    int b = blockIdx.x;
    if (threadIdx.x < 128) cur[threadIdx.x] = 0;
    __syncthreads();
    int lo = b << BSH;
    int ne = min(curD[b], PCAP);
    const unsigned* seg = partD + (size_t)b * PCAP;
    for (int i = threadIdx.x; i < ne; i += 256) {
        unsigned u = seg[i];
        int r = u >> 16;
        int pos = atomicAdd(&cur[r], 1);
        if (pos < ELLW) rows[r][pos] = (int)(u & 0xFFFFu);
    }
    __syncthreads();
    const int Q = ELLW / 8;           // 12 chunks of 8 ushorts (16B) per row
    for (int idx = threadIdx.x; idx < 128 * Q; idx += 256) {
        int r = idx / Q, q = idx % Q;
        if (lo + r < N) {
            unsigned short tmp[8];
#pragma unroll
            for (int j = 0; j < 8; j++) tmp[j] = (unsigned short)rows[r][q * 8 + j];
            *(uint4*)(ell_in + (size_t)(lo + r) * ELLW + q * 8) = *(const uint4*)tmp;
        }
    }
    if (threadIdx.x < 128) {
        int node = lo + threadIdx.x;
        if (node < N) {
            int c = cur[threadIdx.x];
            cnt[node] = c;
            float d = rsqrtf((float)(min(c, ELLW) + 1));  // +1 self-loop
            dinv[node] = d;
            float2 pk; pk.x = d; pk.y = __int_as_float(batch[node]);
            pack[node] = pk;
        }
    }
}

// Phase 3: one block per src-bucket; Ct rows in LDS, transposed bf16 hi/lo out.
__global__ __launch_bounds__(256) void k_buildCt(const unsigned* __restrict__ partS, const int* __restrict__ curS,
                                                 const float2* __restrict__ pack,
                                                 unsigned short* __restrict__ ct_hi,
                                                 unsigned short* __restrict__ ct_lo,
                                                 int N, int N_pad) {
    __shared__ float ct[128][65];   // +1 pad kills bank conflicts in transpose read
    __shared__ float dv[128];
    int b = blockIdx.x;
    for (int idx = threadIdx.x; idx < 128 * 65; idx += 256) (&ct[0][0])[idx] = 0.f;
    __syncthreads();
    int lo = b << BSH;
    int ne = min(curS[b], PCAP);
    const unsigned* seg = partS + (size_t)b * PCAP;
    for (int i = threadIdx.x; i < ne; i += 256) {
        unsigned u = seg[i];
        float2 pk = pack[u & 0xFFFFu];
        atomicAdd(&ct[u >> 16][__float_as_int(pk.y)], pk.x);
    }
    __syncthreads();
    if (threadIdx.x < 128) {
        int node = lo + threadIdx.x;
        if (node < N) {
            float2 ps = pack[node];
            dv[threadIdx.x] = ps.x;
            ct[threadIdx.x][__float_as_int(ps.y)] += ps.x;   // self-loop (exclusive row owner)
        } else dv[threadIdx.x] = 0.f;
    }
    __syncthreads();
    int g = threadIdx.x >> 2, js = (threadIdx.x & 3) * 32;
    unsigned short hv[32], lv[32];
#pragma unroll
    for (int j = 0; j < 32; j++) {
        float val = dv[js + j] * ct[js + j][g];
        unsigned short h = f2bf(val);
        hv[j] = h;
        lv[j] = f2bf(val - bf2f(h));
    }
    size_t basep = (size_t)g * N_pad + lo + js;
#pragma unroll
    for (int j = 0; j < 32; j += 8) {
        *(uint4*)(ct_hi + basep + j) = *(const uint4*)&hv[j];
        *(uint4*)(ct_lo + basep + j) = *(const uint4*)&lv[j];
    }
}

// ---------------- layer 0 fused: wave-per-node gather + 3->256 matmul + BN + ReLU ----------------
// Also zero-fills bf16 pad rows [N, N_pad) (replaces a memset).

__global__ __launch_bounds__(256) void k_l0(const float4* __restrict__ x4, const unsigned short* __restrict__ ell_in,
                                            const int* __restrict__ cnt, const float* __restrict__ dinv,
                                            const float* __restrict__ W, const float* __restrict__ b,
                                            const float* __restrict__ g, const float* __restrict__ be,
                                            const float* __restrict__ m, const float* __restrict__ v,
                                            unsigned short* __restrict__ h, int N) {
    int wv = threadIdx.x >> 6, lane = threadIdx.x & 63;
    int node = blockIdx.x * 4 + wv;
    int c4 = lane * 4;
    if (node >= N) {
        ushort4 z = {0, 0, 0, 0};
        *(ushort4*)(h + (size_t)node * NFEAT + c4) = z;
        return;
    }
    float dvn = dinv[node];
    int len = min(cnt[node], ELLW);
    const unsigned short* nb = ell_in + (size_t)node * ELLW;
    float a0 = 0.f, a1 = 0.f, a2 = 0.f;
    for (int e = lane; e < len; e += 64) {
        int s = nb[e];
        float4 xv = x4[s];                 // single dwordx4 gather
        float w = dinv[s] * dvn;
        a0 += w * xv.x;
        a1 += w * xv.y;
        a2 += w * xv.z;
    }
#pragma unroll
    for (int off = 32; off; off >>= 1) {
        a0 += __shfl_xor(a0, off);
        a1 += __shfl_xor(a1, off);
        a2 += __shfl_xor(a2, off);
    }
    float4 xs = x4[node];
    float wself = dvn * dvn;   // identical in all lanes
    a0 += wself * xs.x;
    a1 += wself * xs.y;
    a2 += wself * xs.z;
    float4 w0 = *(const float4*)(W + c4);
    float4 w1 = *(const float4*)(W + NFEAT + c4);
    float4 w2 = *(const float4*)(W + 2 * NFEAT + c4);
    float4 bb = *(const float4*)(b + c4);
    float4 gg = *(const float4*)(g + c4);
    float4 ee = *(const float4*)(be + c4);
    float4 mm = *(const float4*)(m + c4);
    float4 vv = *(const float4*)(v + c4);
    float r0 = ((a0 * w0.x + a1 * w1.x + a2 * w2.x) + bb.x - mm.x) * rsqrtf(vv.x + BN_EPSF) * gg.x + ee.x;
    float r1 = ((a0 * w0.y + a1 * w1.y + a2 * w2.y) + bb.y - mm.y) * rsqrtf(vv.y + BN_EPSF) * gg.y + ee.y;
    float r2 = ((a0 * w0.z + a1 * w1.z + a2 * w2.z) + bb.z - mm.z) * rsqrtf(vv.z + BN_EPSF) * gg.z + ee.z;
    float r3 = ((a0 * w0.w + a1 * w1.w + a2 * w2.w) + bb.w - mm.w) * rsqrtf(vv.w + BN_EPSF) * gg.w + ee.w;
    ushort4 o;
    o.x = f2bf(fmaxf(r0, 0.f)); o.y = f2bf(fmaxf(r1, 0.f));
    o.z = f2bf(fmaxf(r2, 0.f)); o.w = f2bf(fmaxf(r3, 0.f));
    *(ushort4*)(h + (size_t)node * NFEAT + c4) = o;
}

// ---------------- bf16 MFMA GEMM -> fp8 e4m3 output: C8[M][256] bytes ----------------

__global__ __launch_bounds__(256) void k_mm_mfma(const unsigned short* __restrict__ A,
                                                 const unsigned short* __restrict__ Bt,
                                                 unsigned char* __restrict__ C8) {
    __shared__ __align__(16) unsigned short As[4][128][8];  // [kchunk][row][j] 8KB
    __shared__ __align__(16) unsigned short Bs[4][128][8];  // [kchunk][col][j] 8KB
    int bm = blockIdx.x * 128, bn = blockIdx.y * 128;
    int tid = threadIdx.x;
    int lane = tid & 63, wave = tid >> 6;
    int wm = (wave & 1) * 64, wn = (wave >> 1) * 64;
    int lrow = lane & 15, lk = lane >> 4;
    f32x4 acc[4][4] = {};

    for (int k0 = 0; k0 < 256; k0 += 32) {
#pragma unroll
        for (int i = 0; i < 2; i++) {
            int idx = tid + 256 * i;
            int ch = idx & 3, row = idx >> 2;
            *(uint4*)(&As[ch][row][0]) = *(const uint4*)(A + (size_t)(bm + row) * 256 + k0 + ch * 8);
            *(uint4*)(&Bs[ch][row][0]) = *(const uint4*)(Bt + (size_t)(bn + row) * 256 + k0 + ch * 8);
        }
        __syncthreads();
        bf16x8 af[4], bf[4];
#pragma unroll
        for (int r = 0; r < 4; r++) af[r] = *(const bf16x8*)(&As[lk][wm + r * 16 + lrow][0]);
#pragma unroll
        for (int c = 0; c < 4; c++) bf[c] = *(const bf16x8*)(&Bs[lk][wn + c * 16 + lrow][0]);
#pragma unroll
        for (int r = 0; r < 4; r++)
#pragma unroll
            for (int c = 0; c < 4; c++)
                acc[r][c] = __builtin_amdgcn_mfma_f32_16x16x32_bf16(af[r], bf[c], acc[r][c], 0, 0, 0);
        __syncthreads();
    }

#pragma unroll
    for (int r = 0; r < 4; r++) {
#pragma unroll
        for (int reg = 0; reg < 4; reg++) {
            int grow = bm + wm + r * 16 + lk * 4 + reg;
            int p01 = __builtin_amdgcn_cvt_pk_fp8_f32(acc[r][0][reg], acc[r][1][reg], 0, false);
            int p23 = __builtin_amdgcn_cvt_pk_fp8_f32(acc[r][2][reg], acc[r][3][reg], 0, false);
            size_t base = (size_t)grow * 256 + bn + wn + lrow;
            C8[base]      = (unsigned char)(p01 & 0xff);
            C8[base + 16] = (unsigned char)((p01 >> 8) & 0xff);
            C8[base + 32] = (unsigned char)(p23 & 0xff);
            C8[base + 48] = (unsigned char)((p23 >> 8) & 0xff);
        }
    }
}

// ---------------- fp8 aggregation with fused BN affine + ReLU (layer 1) -> bf16 A1 ----------------
// Grid covers N_pad; pad nodes write zero rows (replaces a memset).

template <bool RELU>
__global__ __launch_bounds__(64) void k_agg256b(const unsigned char* __restrict__ t,
                                                const unsigned short* __restrict__ ell_in,
                                                const int* __restrict__ cnt,
                                                const float* __restrict__ dinv,
                                                const float* __restrict__ b, const float* __restrict__ g,
                                                const float* __restrict__ be, const float* __restrict__ m,
                                                const float* __restrict__ v, unsigned short* __restrict__ out, int N) {
    __shared__ int s_idx[64];
    __shared__ float s_w[64];
    int node = blockIdx.x;
    int c4 = threadIdx.x * 4;
    if (node >= N) {
        ushort4 z = {0, 0, 0, 0};
        *(ushort4*)(out + (size_t)node * NFEAT + c4) = z;
        return;
    }
    float dv = dinv[node];
    float a0, a1, a2, a3;
    {
        unsigned u = *(const unsigned*)(t + (size_t)node * NFEAT + c4);
        f32x2 flo = __builtin_amdgcn_cvt_pk_f32_fp8(u, false);
        f32x2 fhi = __builtin_amdgcn_cvt_pk_f32_fp8(u, true);
        float w = dv * dv;
        a0 = w * flo[0]; a1 = w * flo[1]; a2 = w * fhi[0]; a3 = w * fhi[1];
    }
    int len = min(cnt[node], ELLW);
    const unsigned short* nb = ell_in + (size_t)node * ELLW;
    for (int base = 0; base < len; base += 64) {
        int chunk = min(64, len - base);
        if ((int)threadIdx.x < chunk) {
            int s = nb[base + threadIdx.x];
            s_idx[threadIdx.x] = s;
            s_w[threadIdx.x] = dinv[s] * dv;
        }
        __syncthreads();
        int j = 0;
        for (; j + 4 <= chunk; j += 4) {
            unsigned u0 = *(const unsigned*)(t + (size_t)s_idx[j + 0] * NFEAT + c4);
            unsigned u1 = *(const unsigned*)(t + (size_t)s_idx[j + 1] * NFEAT + c4);
            unsigned u2 = *(const unsigned*)(t + (size_t)s_idx[j + 2] * NFEAT + c4);
            unsigned u3 = *(const unsigned*)(t + (size_t)s_idx[j + 3] * NFEAT + c4);
            float w0 = s_w[j + 0], w1 = s_w[j + 1], w2 = s_w[j + 2], w3 = s_w[j + 3];
            f32x2 l0 = __builtin_amdgcn_cvt_pk_f32_fp8(u0, false), h0 = __builtin_amdgcn_cvt_pk_f32_fp8(u0, true);
            f32x2 l1 = __builtin_amdgcn_cvt_pk_f32_fp8(u1, false), h1 = __builtin_amdgcn_cvt_pk_f32_fp8(u1, true);
            f32x2 l2 = __builtin_amdgcn_cvt_pk_f32_fp8(u2, false), h2 = __builtin_amdgcn_cvt_pk_f32_fp8(u2, true);
            f32x2 l3 = __builtin_amdgcn_cvt_pk_f32_fp8(u3, false), h3 = __builtin_amdgcn_cvt_pk_f32_fp8(u3, true);
            a0 += w0 * l0[0]; a1 += w0 * l0[1]; a2 += w0 * h0[0]; a3 += w0 * h0[1];
            a0 += w1 * l1[0]; a1 += w1 * l1[1]; a2 += w1 * h1[0]; a3 += w1 * h1[1];
            a0 += w2 * l2[0]; a1 += w2 * l2[1]; a2 += w2 * h2[0]; a3 += w2 * h2[1];
            a0 += w3 * l3[0]; a1 += w3 * l3[1]; a2 += w3 * h3[0]; a3 += w3 * h3[1];
        }
        for (; j < chunk; j++) {
            unsigned u = *(const unsigned*)(t + (size_t)s_idx[j] * NFEAT + c4);
            float w = s_w[j];
            f32x2 flo = __builtin_amdgcn_cvt_pk_f32_fp8(u, false);
            f32x2 fhi = __builtin_amdgcn_cvt_pk_f32_fp8(u, true);
            a0 += w * flo[0]; a1 += w * flo[1]; a2 += w * fhi[0]; a3 += w * fhi[1];
        }
        __syncthreads();
    }
    float4 bb = *(const float4*)(b + c4);
    float4 gg = *(const float4*)(g + c4);
    float4 ee = *(const float4*)(be + c4);
    float4 mm = *(const float4*)(m + c4);
    float4 vv = *(const float4*)(v + c4);
    float r0 = (a0 + bb.x - mm.x) * rsqrtf(vv.x + BN_EPSF) * gg.x + ee.x;
    float r1 = (a1 + bb.y - mm.y) * rsqrtf(vv.y + BN_EPSF) * gg.y + ee.y;
    float r2 = (a2 + bb.z - mm.z) * rsqrtf(vv.z + BN_EPSF) * gg.z + ee.z;
    float r3 = (a3 + bb.w - mm.w) * rsqrtf(vv.w + BN_EPSF) * gg.w + ee.w;
    if (RELU) { r0 = fmaxf(r0, 0.f); r1 = fmaxf(r1, 0.f); r2 = fmaxf(r2, 0.f); r3 = fmaxf(r3, 0.f); }
    ushort4 o; o.x = f2bf(r0); o.y = f2bf(r1); o.z = f2bf(r2); o.w = f2bf(r3);
    *(ushort4*)(out + (size_t)node * NFEAT + c4) = o;
}

// ---------------- pooled GEMM via MFMA: P[ch][c][g] = sum_{j in chunk} A1[j][c]*Ct[j][g] ----------------

__global__ __launch_bounds__(256) void k_cgemm(const unsigned short* __restrict__ Y,
                                               const unsigned short* __restrict__ ct_hi,
                                               const unsigned short* __restrict__ ct_lo,
                                               float* __restrict__ P, int N_pad) {
    __shared__ __align__(16) unsigned short s_hi[64 * 40];  // [g][j] stride 40 (16B-aligned rows)
    __shared__ __align__(16) unsigned short s_lo[64 * 40];
    int tid = threadIdx.x;
    int lane = tid & 63, wv = tid >> 6;
    int lc = lane & 15, q = lane >> 4;
    int cbase = blockIdx.y * 64 + wv * 16;
    int j0 = blockIdx.x * CH_J;
    int sg = tid >> 2, sj8 = (tid & 3) * 8;  // staging coords: 64 g x 32 j
    f32x4 acc[4] = {};

    for (int ks = 0; ks < CH_J; ks += 32) {
        size_t cbs = (size_t)sg * N_pad + j0 + ks + sj8;
        *(uint4*)(&s_hi[sg * 40 + sj8]) = *(const uint4*)(ct_hi + cbs);
        *(uint4*)(&s_lo[sg * 40 + sj8]) = *(const uint4*)(ct_lo + cbs);
        __syncthreads();
        const unsigned short* yp = Y + (size_t)(j0 + ks + q * 8) * 256 + cbase + lc;
        bf16x8 a;
#pragma unroll
        for (int jj = 0; jj < 8; jj++) a[jj] = (short)yp[(size_t)jj * 256];
#pragma unroll
        for (int nt = 0; nt < 4; nt++) {
            bf16x8 bh = *(const bf16x8*)(&s_hi[(nt * 16 + lc) * 40 + q * 8]);
            bf16x8 bl = *(const bf16x8*)(&s_lo[(nt * 16 + lc) * 40 + q * 8]);
            acc[nt] = __builtin_amdgcn_mfma_f32_16x16x32_bf16(a, bh, acc[nt], 0, 0, 0);
            acc[nt] = __builtin_amdgcn_mfma_f32_16x16x32_bf16(a, bl, acc[nt], 0, 0, 0);
        }
        __syncthreads();
    }
    // D: m(c) = q*4+reg, n(g) = nt*16+lc; store P[ch][c][g]
    float* pp = P + (size_t)blockIdx.x * 64 * 256;
#pragma unroll
    for (int nt = 0; nt < 4; nt++) {
        int g = nt * 16 + lc;
#pragma unroll
        for (int reg = 0; reg < 4; reg++) {
            int c = cbase + q * 4 + reg;
            pp[(size_t)c * 64 + g] = acc[nt][reg];
        }
    }
}

// reduce partials over chunks: pooled[g][c] = sum_ch P[ch][c][g]; 256 blocks (one per c)
__global__ __launch_bounds__(64) void k_redP(const float* __restrict__ P,
                                             float* __restrict__ pooled, int nch) {
    int c = blockIdx.x;
    int g = threadIdx.x;
    float acc = 0.f;
    const float* pp = P + (size_t)c * 64 + g;
    for (int ch = 0; ch < nch; ch++) acc += pp[(size_t)ch * 64 * 256];
    pooled[(size_t)g * 256 + c] = acc;
}

// W2 mini-GEMM + mean + bias + BN -> d_out
__global__ __launch_bounds__(256) void k_out(const float* __restrict__ pooled,
                                             const float* __restrict__ W2,
                                             const int* __restrict__ batch,
                                             const float* __restrict__ b, const float* __restrict__ gw,
                                             const float* __restrict__ be, const float* __restrict__ m,
                                             const float* __restrict__ v,
                                             float* __restrict__ out, int N) {
    __shared__ float s_pool[256];
    __shared__ int s_cnt;
    int g = blockIdx.x;
    int c = threadIdx.x;
    s_pool[c] = pooled[(size_t)g * 256 + c];
    if (threadIdx.x == 0) {
        int lo = 0, hi = N;
        while (lo < hi) { int mid = (lo + hi) >> 1; if (batch[mid] < g) lo = mid + 1; else hi = mid; }
        int st = lo;
        lo = 0; hi = N;
        while (lo < hi) { int mid = (lo + hi) >> 1; if (batch[mid] < g + 1) lo = mid + 1; else hi = mid; }
        s_cnt = lo - st;
    }
    __syncthreads();
    float dot = 0.f;
    for (int k = 0; k < 256; k += 4) {
        float4 pk = *(const float4*)(s_pool + k);
        dot += pk.x * W2[(k + 0) * 256 + c];
        dot += pk.y * W2[(k + 1) * 256 + c];
        dot += pk.z * W2[(k + 2) * 256 + c];
        dot += pk.w * W2[(k + 3) * 256 + c];
    }
    float r = 0.f;
    int cntg = s_cnt;
    if (cntg > 0) {
        float mean = dot / (float)cntg + b[c];
        r = (mean - m[c]) * rsqrtf(v[c] + BN_EPSF) * gw[c] + be[c];
    }
    out[g * 256 + c] = r;
}

// ---------------- launch ----------------

static inline size_t align_up(size_t x, size_t a) { return (x + a - 1) & ~(a - 1); }

extern "C" void kernel_launch(void* const* d_in, const int* in_sizes, int n_in,
                              void* d_out, int out_size, void* d_ws, size_t ws_size,
                              hipStream_t stream) {
    const float* x = (const float*)d_in[0];
    const int* edge_index = (const int*)d_in[1];
    const int* batch = (const int*)d_in[2];

    const int N = in_sizes[2];          // 50000 (< 2^16, required by u32/u16 packing)
    const int E = in_sizes[1] / 2;      // 1600000
    const int NCH = (N + CH_J - 1) / CH_J;   // pooled-GEMM chunks (98)
    const int N_pad = NCH * CH_J;            // 50176 = PBKT*128

    const int* e_src = edge_index;
    const int* e_dst = edge_index + E;

    const float* W[3]; const float* bP[3]; const float* gP[3];
    const float* beP[3]; const float* mP[3]; const float* vP[3];
    for (int i = 0; i < 3; i++) {
        W[i]  = (const float*)d_in[3 + 6 * i + 0];
        bP[i] = (const float*)d_in[3 + 6 * i + 1];
        gP[i] = (const float*)d_in[3 + 6 * i + 2];
        beP[i]= (const float*)d_in[3 + 6 * i + 3];
        mP[i] = (const float*)d_in[3 + 6 * i + 4];
        vP[i] = (const float*)d_in[3 + 6 * i + 5];
    }

    // workspace carve-up
    char* ws = (char*)d_ws;
    size_t off = 0;
    auto carve = [&](size_t bytes) { void* p = ws + off; off = align_up(off + bytes, 256); return p; };
    int*   curD     = (int*)  carve((size_t)2 * PBKT * 4);   // bucket cursors, one memset
    int*   curS     = curD + PBKT;
    int*   cnt      = (int*)  carve((size_t)N * 4);
    float* dinv     = (float*)carve((size_t)N * 4);
    float2* pack    = (float2*)carve((size_t)N * 8);
    float4* x4      = (float4*)carve((size_t)N * 16);
    unsigned* partD = (unsigned*)carve((size_t)PBKT * PCAP * 4);  // 7.2 MB (packed u32)
    unsigned* partS = (unsigned*)carve((size_t)PBKT * PCAP * 4);  // 7.2 MB
    unsigned short* ell_in = (unsigned short*)carve((size_t)N * ELLW * 2);  // 9.6 MB (u16)
    unsigned short* bufA = (unsigned short*)carve((size_t)N_pad * NFEAT * 2);  // A0/A1 bf16
    unsigned char*  bufY = (unsigned char*)carve((size_t)N_pad * NFEAT);    // fp8 Y (12.8 MB)
    unsigned short* Wt1  = (unsigned short*)carve((size_t)NFEAT * NFEAT * 2);
    unsigned short* ct_hi = (unsigned short*)carve((size_t)N_pad * 64 * 2);
    unsigned short* ct_lo = (unsigned short*)carve((size_t)N_pad * 64 * 2);
    float* partials = (float*)carve((size_t)NCH * 64 * 256 * 4);     // 6.4 MB
    float* pooled   = (float*)carve((size_t)64 * 256 * 4);
    (void)ws_size;

    hipMemsetAsync(curD, 0, (size_t)2 * PBKT * 4, stream);

    const int BS = 256;
    // phase 1: partition edges (packed u32 entries; LDS-cached chunk)
    k_part<<<(E + PEDG - 1) / PEDG, BS, 0, stream>>>(e_src, e_dst, curD, curS, partD, partS, E);
    // merged prep: W1 transpose (256 blocks) + x float4 repack
    k_prep<<<256 + (N + BS - 1) / BS, BS, 0, stream>>>(W[1], Wt1, x, x4, N);
    // phase 2: ELL rows in LDS -> coalesced u16 write; cnt/dinv/pack fall out
    k_buildIn<<<PBKT, BS, 0, stream>>>(partD, curD, batch, ell_in, cnt, dinv, pack, N);
    // phase 3: Ct rows in LDS -> transposed bf16 hi/lo directly
    k_buildCt<<<PBKT, BS, 0, stream>>>(partS, curS, pack, ct_hi, ct_lo, N, N_pad);

    // layer 0 fused: gather-aggregate (float4 x) + 3->256 matmul + BN + ReLU -> bf16 (+pad zero)
    k_l0<<<N_pad / 4, BS, 0, stream>>>(x4, ell_in, cnt, dinv, W[0],
                                       bP[0], gP[0], beP[0], mP[0], vP[0], bufA, N);

    dim3 mmGrid((N + 127) / 128, 2);
    // layer 1: Y = h@W1 (MFMA, fp8 out) -> propagate (fp8 gather) -> BN + ReLU -> bf16 A1 (+pad zero)
    k_mm_mfma<<<mmGrid, 256, 0, stream>>>(bufA, Wt1, bufY);
    k_agg256b<true><<<N_pad, 64, 0, stream>>>(bufY, ell_in, cnt, dinv,
                                              bP[1], gP[1], beP[1], mP[1], vP[1], bufA, N);

    // layer 2 + pool (W2 folded out): P = per-chunk Ct^T @ A1 via MFMA; out = BN((P@W2)/n + b2)
    dim3 cgGrid(NCH, 4);
    k_cgemm<<<cgGrid, 256, 0, stream>>>(bufA, ct_hi, ct_lo, partials, N_pad);
    k_redP<<<256, 64, 0, stream>>>(partials, pooled, NCH);
    k_out<<<64, 256, 0, stream>>>(pooled, W[2], batch, bP[2], gP[2], beP[2], mP[2], vP[2],
                                  (float*)d_out, N);
}

// Round 20
// 325.689 us; speedup vs baseline: 1.0579x; 1.0117x over previous
//
#include <hip/hip_runtime.h>

#define NFEAT 256
#define BN_EPSF 1e-5f
#define CH_J 512            // j's per pooled-GEMM chunk (must be multiple of 64)
#define ELLW 96             // ELL width; in/out-degree ~ Poisson(32), P(>=96) ~ 0
#define BSH 7               // bucket = node >> 7 (128 nodes/bucket)
#define PBKT 392            // buckets (covers N_pad = 50176 = 392*128)
#define PCAP 4608           // per-bucket edge capacity (mean 4082, +8 sigma)
#define PEDG 4992           // edges per partition block (LDS-cached chunk)
#define W1_SCALE 8.0f       // W1 prescale for fp8 hi/lo encode (Y comes out x8)
#define Y_DESCALE 0.125f

typedef __attribute__((ext_vector_type(8))) short bf16x8;
typedef __attribute__((ext_vector_type(4))) float f32x4;
typedef __attribute__((ext_vector_type(2))) float f32x2;

__device__ __forceinline__ unsigned short f2bf(float f) {
    union { float f; unsigned u; } v; v.f = f;
    unsigned r = v.u + 0x7fffu + ((v.u >> 16) & 1u);  // round-to-nearest-even
    return (unsigned short)(r >> 16);
}
__device__ __forceinline__ float bf2f(unsigned short h) {
    union { unsigned u; float f; } v; v.u = ((unsigned)h) << 16;
    return v.f;
}

// ---------------- graph preprocessing: partition-based (coalesced) build ----------------

__global__ __launch_bounds__(256) void k_part(const int* __restrict__ src, const int* __restrict__ dst,
                                              int* __restrict__ curD, int* __restrict__ curS,
                                              unsigned* __restrict__ partD, unsigned* __restrict__ partS, int E) {
    __shared__ int cD[PBKT], cS[PBKT], bD[PBKT], bS[PBKT];
    __shared__ int2 eds[PEDG];   // 40KB edge cache
    for (int t = threadIdx.x; t < PBKT; t += 256) { cD[t] = 0; cS[t] = 0; }
    __syncthreads();
    int e0 = blockIdx.x * PEDG;
    int ne = min(E - e0, PEDG);
    for (int i = threadIdx.x; i < ne; i += 256) {
        int2 e; e.x = src[e0 + i]; e.y = dst[e0 + i];
        eds[i] = e;
        atomicAdd(&cD[e.y >> BSH], 1);
        atomicAdd(&cS[e.x >> BSH], 1);
    }
    __syncthreads();
    for (int t = threadIdx.x; t < PBKT; t += 256) {
        bD[t] = cD[t] ? atomicAdd(&curD[t], cD[t]) : 0;
        bS[t] = cS[t] ? atomicAdd(&curS[t], cS[t]) : 0;
        cD[t] = 0; cS[t] = 0;
    }
    __syncthreads();
    for (int i = threadIdx.x; i < ne; i += 256) {
        int2 e = eds[i];
        int b1 = e.y >> BSH;
        int p1 = bD[b1] + atomicAdd(&cD[b1], 1);
        if (p1 < PCAP) partD[(size_t)b1 * PCAP + p1] = ((unsigned)(e.y & 127) << 16) | (unsigned)e.x;
        int b2 = e.x >> BSH;
        int p2 = bS[b2] + atomicAdd(&cS[b2], 1);
        if (p2 < PCAP) partS[(size_t)b2 * PCAP + p2] = ((unsigned)(e.x & 127) << 16) | (unsigned)e.y;
    }
}

// merged prep: blocks [0,256) = W1 column n -> fp8 hi/lo (x8 scale), coalesced byte writes;
// blocks >= 256 repack x to float4.
__global__ __launch_bounds__(256) void k_prep(const float* __restrict__ W,
                                              unsigned char* __restrict__ Wt_hi, unsigned char* __restrict__ Wt_lo,
                                              const float* __restrict__ x, float4* __restrict__ x4, int N) {
    if (blockIdx.x < 256) {
        int n = blockIdx.x, k = threadIdx.x;
        float w8 = W[k * 256 + n] * W1_SCALE;
        int ph = __builtin_amdgcn_cvt_pk_fp8_f32(w8, w8, 0, false);
        f32x2 dec = __builtin_amdgcn_cvt_pk_f32_fp8(ph, false);
        int pl = __builtin_amdgcn_cvt_pk_fp8_f32(w8 - dec[0], w8 - dec[0], 0, false);
        Wt_hi[n * 256 + k] = (unsigned char)(ph & 0xff);
        Wt_lo[n * 256 + k] = (unsigned char)(pl & 0xff);
    } else {
        int i = (blockIdx.x - 256) * 256 + threadIdx.x;
        if (i < N) {
            float4 r; r.x = x[i * 3 + 0]; r.y = x[i * 3 + 1]; r.z = x[i * 3 + 2]; r.w = 0.f;
            x4[i] = r;
        }
    }
}

// Phase 2: one block per dst-bucket; 128 ELL rows in LDS, coalesced ushort write.
__global__ __launch_bounds__(256) void k_buildIn(const unsigned* __restrict__ partD, const int* __restrict__ curD,
                                                 const int* __restrict__ batch,
                                                 unsigned short* __restrict__ ell_in, int* __restrict__ cnt,
                                                 float* __restrict__ dinv, float2* __restrict__ pack, int N) {
    __shared__ int rows[128][ELLW];   // 49KB
    __shared__ int cur[128];
    int b = blockIdx.x;
    if (threadIdx.x < 128) cur[threadIdx.x] = 0;
    __syncthreads();
    int lo = b << BSH;
    int ne = min(curD[b], PCAP);
    const unsigned* seg = partD + (size_t)b * PCAP;
    for (int i = threadIdx.x; i < ne; i += 256) {
        unsigned u = seg[i];
        int r = u >> 16;
        int pos = atomicAdd(&cur[r], 1);
        if (pos < ELLW) rows[r][pos] = (int)(u & 0xFFFFu);
    }
    __syncthreads();
    const int Q = ELLW / 8;           // 12 chunks of 8 ushorts (16B) per row
    for (int idx = threadIdx.x; idx < 128 * Q; idx += 256) {
        int r = idx / Q, q = idx % Q;
        if (lo + r < N) {
            unsigned short tmp[8];
#pragma unroll
            for (int j = 0; j < 8; j++) tmp[j] = (unsigned short)rows[r][q * 8 + j];
            *(uint4*)(ell_in + (size_t)(lo + r) * ELLW + q * 8) = *(const uint4*)tmp;
        }
    }
    if (threadIdx.x < 128) {
        int node = lo + threadIdx.x;
        if (node < N) {
            int c = cur[threadIdx.x];
            cnt[node] = c;
            float d = rsqrtf((float)(min(c, ELLW) + 1));  // +1 self-loop
            dinv[node] = d;
            float2 pk; pk.x = d; pk.y = __int_as_float(batch[node]);
            pack[node] = pk;
        }
    }
}

// Phase 3: one block per src-bucket; Ct rows in LDS, transposed bf16 hi/lo out.
__global__ __launch_bounds__(256) void k_buildCt(const unsigned* __restrict__ partS, const int* __restrict__ curS,
                                                 const float2* __restrict__ pack,
                                                 unsigned short* __restrict__ ct_hi,
                                                 unsigned short* __restrict__ ct_lo,
                                                 int N, int N_pad) {
    __shared__ float ct[128][65];   // +1 pad kills bank conflicts in transpose read
    __shared__ float dv[128];
    int b = blockIdx.x;
    for (int idx = threadIdx.x; idx < 128 * 65; idx += 256) (&ct[0][0])[idx] = 0.f;
    __syncthreads();
    int lo = b << BSH;
    int ne = min(curS[b], PCAP);
    const unsigned* seg = partS + (size_t)b * PCAP;
    for (int i = threadIdx.x; i < ne; i += 256) {
        unsigned u = seg[i];
        float2 pk = pack[u & 0xFFFFu];
        atomicAdd(&ct[u >> 16][__float_as_int(pk.y)], pk.x);
    }
    __syncthreads();
    if (threadIdx.x < 128) {
        int node = lo + threadIdx.x;
        if (node < N) {
            float2 ps = pack[node];
            dv[threadIdx.x] = ps.x;
            ct[threadIdx.x][__float_as_int(ps.y)] += ps.x;   // self-loop (exclusive row owner)
        } else dv[threadIdx.x] = 0.f;
    }
    __syncthreads();
    int g = threadIdx.x >> 2, js = (threadIdx.x & 3) * 32;
    unsigned short hv[32], lv[32];
#pragma unroll
    for (int j = 0; j < 32; j++) {
        float val = dv[js + j] * ct[js + j][g];
        unsigned short h = f2bf(val);
        hv[j] = h;
        lv[j] = f2bf(val - bf2f(h));
    }
    size_t basep = (size_t)g * N_pad + lo + js;
#pragma unroll
    for (int j = 0; j < 32; j += 8) {
        *(uint4*)(ct_hi + basep + j) = *(const uint4*)&hv[j];
        *(uint4*)(ct_lo + basep + j) = *(const uint4*)&lv[j];
    }
}

// ---------------- layer 0 fused: wave-per-node gather + 3->256 matmul + BN + ReLU -> fp8 A0 ----------------
// Also zero-fills fp8 pad rows [N, N_pad).

__global__ __launch_bounds__(256) void k_l0(const float4* __restrict__ x4, const unsigned short* __restrict__ ell_in,
                                            const int* __restrict__ cnt, const float* __restrict__ dinv,
                                            const float* __restrict__ W, const float* __restrict__ b,
                                            const float* __restrict__ g, const float* __restrict__ be,
                                            const float* __restrict__ m, const float* __restrict__ v,
                                            unsigned char* __restrict__ h8, int N) {
    int wv = threadIdx.x >> 6, lane = threadIdx.x & 63;
    int node = blockIdx.x * 4 + wv;
    int c4 = lane * 4;
    if (node >= N) {
        *(unsigned*)(h8 + (size_t)node * NFEAT + c4) = 0u;
        return;
    }
    float dvn = dinv[node];
    int len = min(cnt[node], ELLW);
    const unsigned short* nb = ell_in + (size_t)node * ELLW;
    float a0 = 0.f, a1 = 0.f, a2 = 0.f;
    for (int e = lane; e < len; e += 64) {
        int s = nb[e];
        float4 xv = x4[s];                 // single dwordx4 gather
        float w = dinv[s] * dvn;
        a0 += w * xv.x;
        a1 += w * xv.y;
        a2 += w * xv.z;
    }
#pragma unroll
    for (int off = 32; off; off >>= 1) {
        a0 += __shfl_xor(a0, off);
        a1 += __shfl_xor(a1, off);
        a2 += __shfl_xor(a2, off);
    }
    float4 xs = x4[node];
    float wself = dvn * dvn;   // identical in all lanes
    a0 += wself * xs.x;
    a1 += wself * xs.y;
    a2 += wself * xs.z;
    float4 w0 = *(const float4*)(W + c4);
    float4 w1 = *(const float4*)(W + NFEAT + c4);
    float4 w2 = *(const float4*)(W + 2 * NFEAT + c4);
    float4 bb = *(const float4*)(b + c4);
    float4 gg = *(const float4*)(g + c4);
    float4 ee = *(const float4*)(be + c4);
    float4 mm = *(const float4*)(m + c4);
    float4 vv = *(const float4*)(v + c4);
    float r0 = ((a0 * w0.x + a1 * w1.x + a2 * w2.x) + bb.x - mm.x) * rsqrtf(vv.x + BN_EPSF) * gg.x + ee.x;
    float r1 = ((a0 * w0.y + a1 * w1.y + a2 * w2.y) + bb.y - mm.y) * rsqrtf(vv.y + BN_EPSF) * gg.y + ee.y;
    float r2 = ((a0 * w0.z + a1 * w1.z + a2 * w2.z) + bb.z - mm.z) * rsqrtf(vv.z + BN_EPSF) * gg.z + ee.z;
    float r3 = ((a0 * w0.w + a1 * w1.w + a2 * w2.w) + bb.w - mm.w) * rsqrtf(vv.w + BN_EPSF) * gg.w + ee.w;
    r0 = fmaxf(r0, 0.f); r1 = fmaxf(r1, 0.f); r2 = fmaxf(r2, 0.f); r3 = fmaxf(r3, 0.f);
    int p01 = __builtin_amdgcn_cvt_pk_fp8_f32(r0, r1, 0, false);
    int p23 = __builtin_amdgcn_cvt_pk_fp8_f32(r2, r3, 0, false);
    unsigned pk = (unsigned)(p01 & 0xffff) | ((unsigned)(p23 & 0xffff) << 16);
    *(unsigned*)(h8 + (size_t)node * NFEAT + c4) = pk;
}

// ---------------- fp8 MFMA GEMM: Y8 = A0_fp8 @ (8*W1)_fp8(hi+lo), Y stored fp8 (x8) ----------------
// LDS-staged contiguous fragments (verified layout from R18; no strided byte gathers).

__global__ __launch_bounds__(256) void k_mm_mfma(const unsigned char* __restrict__ A8,
                                                 const unsigned char* __restrict__ Bh,
                                                 const unsigned char* __restrict__ Bl,
                                                 unsigned char* __restrict__ C8) {
    __shared__ __align__(16) unsigned char As[4][128][8];   // 4KB
    __shared__ __align__(16) unsigned char Bhs[4][128][8];  // 4KB
    __shared__ __align__(16) unsigned char Bls[4][128][8];  // 4KB
    int bm = blockIdx.x * 128, bn = blockIdx.y * 128;
    int tid = threadIdx.x;
    int lane = tid & 63, wave = tid >> 6;
    int wm = (wave & 1) * 64, wn = (wave >> 1) * 64;
    int lrow = lane & 15, lk = lane >> 4;
    f32x4 acc[4][4] = {};

    for (int k0 = 0; k0 < 256; k0 += 32) {
#pragma unroll
        for (int i = 0; i < 2; i++) {
            int idx = tid + 256 * i;
            int ch = idx & 3, row = idx >> 2;
            *(uint2*)(&As[ch][row][0])  = *(const uint2*)(A8 + (size_t)(bm + row) * 256 + k0 + ch * 8);
            *(uint2*)(&Bhs[ch][row][0]) = *(const uint2*)(Bh + (size_t)(bn + row) * 256 + k0 + ch * 8);
            *(uint2*)(&Bls[ch][row][0]) = *(const uint2*)(Bl + (size_t)(bn + row) * 256 + k0 + ch * 8);
        }
        __syncthreads();
        long af[4], bh[4], bl[4];
#pragma unroll
        for (int r = 0; r < 4; r++) af[r] = *(const long*)(&As[lk][wm + r * 16 + lrow][0]);
#pragma unroll
        for (int c = 0; c < 4; c++) {
            bh[c] = *(const long*)(&Bhs[lk][wn + c * 16 + lrow][0]);
            bl[c] = *(const long*)(&Bls[lk][wn + c * 16 + lrow][0]);
        }
#pragma unroll
        for (int r = 0; r < 4; r++)
#pragma unroll
            for (int c = 0; c < 4; c++) {
                acc[r][c] = __builtin_amdgcn_mfma_f32_16x16x32_fp8_fp8(af[r], bh[c], acc[r][c], 0, 0, 0);
                acc[r][c] = __builtin_amdgcn_mfma_f32_16x16x32_fp8_fp8(af[r], bl[c], acc[r][c], 0, 0, 0);
            }
        __syncthreads();
    }

#pragma unroll
    for (int r = 0; r < 4; r++) {
#pragma unroll
        for (int reg = 0; reg < 4; reg++) {
            int grow = bm + wm + r * 16 + lk * 4 + reg;
            int p01 = __builtin_amdgcn_cvt_pk_fp8_f32(acc[r][0][reg], acc[r][1][reg], 0, false);
            int p23 = __builtin_amdgcn_cvt_pk_fp8_f32(acc[r][2][reg], acc[r][3][reg], 0, false);
            size_t base = (size_t)grow * 256 + bn + wn + lrow;
            C8[base]      = (unsigned char)(p01 & 0xff);
            C8[base + 16] = (unsigned char)((p01 >> 8) & 0xff);
            C8[base + 32] = (unsigned char)(p23 & 0xff);
            C8[base + 48] = (unsigned char)((p23 >> 8) & 0xff);
        }
    }
}

// ---------------- fp8 aggregation with fused BN affine + ReLU (layer 1) -> bf16 A1 ----------------
// Y carries x8 scale -> multiply by 0.125 before BN. Pad nodes write zero rows.

template <bool RELU>
__global__ __launch_bounds__(64) void k_agg256b(const unsigned char* __restrict__ t,
                                                const unsigned short* __restrict__ ell_in,
                                                const int* __restrict__ cnt,
                                                const float* __restrict__ dinv,
                                                const float* __restrict__ b, const float* __restrict__ g,
                                                const float* __restrict__ be, const float* __restrict__ m,
                                                const float* __restrict__ v, unsigned short* __restrict__ out, int N) {
    __shared__ int s_idx[64];
    __shared__ float s_w[64];
    int node = blockIdx.x;
    int c4 = threadIdx.x * 4;
    if (node >= N) {
        ushort4 z = {0, 0, 0, 0};
        *(ushort4*)(out + (size_t)node * NFEAT + c4) = z;
        return;
    }
    float dv = dinv[node];
    float a0, a1, a2, a3;
    {
        unsigned u = *(const unsigned*)(t + (size_t)node * NFEAT + c4);
        f32x2 flo = __builtin_amdgcn_cvt_pk_f32_fp8(u, false);
        f32x2 fhi = __builtin_amdgcn_cvt_pk_f32_fp8(u, true);
        float w = dv * dv;
        a0 = w * flo[0]; a1 = w * flo[1]; a2 = w * fhi[0]; a3 = w * fhi[1];
    }
    int len = min(cnt[node], ELLW);
    const unsigned short* nb = ell_in + (size_t)node * ELLW;
    for (int base = 0; base < len; base += 64) {
        int chunk = min(64, len - base);
        if ((int)threadIdx.x < chunk) {
            int s = nb[base + threadIdx.x];
            s_idx[threadIdx.x] = s;
            s_w[threadIdx.x] = dinv[s] * dv;
        }
        __syncthreads();
        int j = 0;
        for (; j + 4 <= chunk; j += 4) {
            unsigned u0 = *(const unsigned*)(t + (size_t)s_idx[j + 0] * NFEAT + c4);
            unsigned u1 = *(const unsigned*)(t + (size_t)s_idx[j + 1] * NFEAT + c4);
            unsigned u2 = *(const unsigned*)(t + (size_t)s_idx[j + 2] * NFEAT + c4);
            unsigned u3 = *(const unsigned*)(t + (size_t)s_idx[j + 3] * NFEAT + c4);
            float w0 = s_w[j + 0], w1 = s_w[j + 1], w2 = s_w[j + 2], w3 = s_w[j + 3];
            f32x2 l0 = __builtin_amdgcn_cvt_pk_f32_fp8(u0, false), h0 = __builtin_amdgcn_cvt_pk_f32_fp8(u0, true);
            f32x2 l1 = __builtin_amdgcn_cvt_pk_f32_fp8(u1, false), h1 = __builtin_amdgcn_cvt_pk_f32_fp8(u1, true);
            f32x2 l2 = __builtin_amdgcn_cvt_pk_f32_fp8(u2, false), h2 = __builtin_amdgcn_cvt_pk_f32_fp8(u2, true);
            f32x2 l3 = __builtin_amdgcn_cvt_pk_f32_fp8(u3, false), h3 = __builtin_amdgcn_cvt_pk_f32_fp8(u3, true);
            a0 += w0 * l0[0]; a1 += w0 * l0[1]; a2 += w0 * h0[0]; a3 += w0 * h0[1];
            a0 += w1 * l1[0]; a1 += w1 * l1[1]; a2 += w1 * h1[0]; a3 += w1 * h1[1];
            a0 += w2 * l2[0]; a1 += w2 * l2[1]; a2 += w2 * h2[0]; a3 += w2 * h2[1];
            a0 += w3 * l3[0]; a1 += w3 * l3[1]; a2 += w3 * h3[0]; a3 += w3 * h3[1];
        }
        for (; j < chunk; j++) {
            unsigned u = *(const unsigned*)(t + (size_t)s_idx[j] * NFEAT + c4);
            float w = s_w[j];
            f32x2 flo = __builtin_amdgcn_cvt_pk_f32_fp8(u, false);
            f32x2 fhi = __builtin_amdgcn_cvt_pk_f32_fp8(u, true);
            a0 += w * flo[0]; a1 += w * flo[1]; a2 += w * fhi[0]; a3 += w * fhi[1];
        }
        __syncthreads();
    }
    a0 *= Y_DESCALE; a1 *= Y_DESCALE; a2 *= Y_DESCALE; a3 *= Y_DESCALE;
    float4 bb = *(const float4*)(b + c4);
    float4 gg = *(const float4*)(g + c4);
    float4 ee = *(const float4*)(be + c4);
    float4 mm = *(const float4*)(m + c4);
    float4 vv = *(const float4*)(v + c4);
    float r0 = (a0 + bb.x - mm.x) * rsqrtf(vv.x + BN_EPSF) * gg.x + ee.x;
    float r1 = (a1 + bb.y - mm.y) * rsqrtf(vv.y + BN_EPSF) * gg.y + ee.y;
    float r2 = (a2 + bb.z - mm.z) * rsqrtf(vv.z + BN_EPSF) * gg.z + ee.z;
    float r3 = (a3 + bb.w - mm.w) * rsqrtf(vv.w + BN_EPSF) * gg.w + ee.w;
    if (RELU) { r0 = fmaxf(r0, 0.f); r1 = fmaxf(r1, 0.f); r2 = fmaxf(r2, 0.f); r3 = fmaxf(r3, 0.f); }
    ushort4 o; o.x = f2bf(r0); o.y = f2bf(r1); o.z = f2bf(r2); o.w = f2bf(r3);
    *(ushort4*)(out + (size_t)node * NFEAT + c4) = o;
}

// ---------------- pooled GEMM via MFMA: P[ch][c][g] = sum_{j in chunk} A1[j][c]*Ct[j][g] ----------------

__global__ __launch_bounds__(256) void k_cgemm(const unsigned short* __restrict__ Y,
                                               const unsigned short* __restrict__ ct_hi,
                                               const unsigned short* __restrict__ ct_lo,
                                               float* __restrict__ P, int N_pad) {
    __shared__ __align__(16) unsigned short s_hi[64 * 40];  // [g][j] stride 40 (16B-aligned rows)
    __shared__ __align__(16) unsigned short s_lo[64 * 40];
    int tid = threadIdx.x;
    int lane = tid & 63, wv = tid >> 6;
    int lc = lane & 15, q = lane >> 4;
    int cbase = blockIdx.y * 64 + wv * 16;
    int j0 = blockIdx.x * CH_J;
    int sg = tid >> 2, sj8 = (tid & 3) * 8;  // staging coords: 64 g x 32 j
    f32x4 acc[4] = {};

    for (int ks = 0; ks < CH_J; ks += 32) {
        size_t cbs = (size_t)sg * N_pad + j0 + ks + sj8;
        *(uint4*)(&s_hi[sg * 40 + sj8]) = *(const uint4*)(ct_hi + cbs);
        *(uint4*)(&s_lo[sg * 40 + sj8]) = *(const uint4*)(ct_lo + cbs);
        __syncthreads();
        const unsigned short* yp = Y + (size_t)(j0 + ks + q * 8) * 256 + cbase + lc;
        bf16x8 a;
#pragma unroll
        for (int jj = 0; jj < 8; jj++) a[jj] = (short)yp[(size_t)jj * 256];
#pragma unroll
        for (int nt = 0; nt < 4; nt++) {
            bf16x8 bh = *(const bf16x8*)(&s_hi[(nt * 16 + lc) * 40 + q * 8]);
            bf16x8 bl = *(const bf16x8*)(&s_lo[(nt * 16 + lc) * 40 + q * 8]);
            acc[nt] = __builtin_amdgcn_mfma_f32_16x16x32_bf16(a, bh, acc[nt], 0, 0, 0);
            acc[nt] = __builtin_amdgcn_mfma_f32_16x16x32_bf16(a, bl, acc[nt], 0, 0, 0);
        }
        __syncthreads();
    }
    // D: m(c) = q*4+reg, n(g) = nt*16+lc; store P[ch][c][g]
    float* pp = P + (size_t)blockIdx.x * 64 * 256;
#pragma unroll
    for (int nt = 0; nt < 4; nt++) {
        int g = nt * 16 + lc;
#pragma unroll
        for (int reg = 0; reg < 4; reg++) {
            int c = cbase + q * 4 + reg;
            pp[(size_t)c * 64 + g] = acc[nt][reg];
        }
    }
}

// reduce partials over chunks: pooled[g][c] = sum_ch P[ch][c][g]; 256 blocks (one per c)
__global__ __launch_bounds__(64) void k_redP(const float* __restrict__ P,
                                             float* __restrict__ pooled, int nch) {
    int c = blockIdx.x;
    int g = threadIdx.x;
    float acc = 0.f;
    const float* pp = P + (size_t)c * 64 + g;
    for (int ch = 0; ch < nch; ch++) acc += pp[(size_t)ch * 64 * 256];
    pooled[(size_t)g * 256 + c] = acc;
}

// W2 mini-GEMM + mean + bias + BN -> d_out
__global__ __launch_bounds__(256) void k_out(const float* __restrict__ pooled,
                                             const float* __restrict__ W2,
                                             const int* __restrict__ batch,
                                             const float* __restrict__ b, const float* __restrict__ gw,
                                             const float* __restrict__ be, const float* __restrict__ m,
                                             const float* __restrict__ v,
                                             float* __restrict__ out, int N) {
    __shared__ float s_pool[256];
    __shared__ int s_cnt;
    int g = blockIdx.x;
    int c = threadIdx.x;
    s_pool[c] = pooled[(size_t)g * 256 + c];
    if (threadIdx.x == 0) {
        int lo = 0, hi = N;
        while (lo < hi) { int mid = (lo + hi) >> 1; if (batch[mid] < g) lo = mid + 1; else hi = mid; }
        int st = lo;
        lo = 0; hi = N;
        while (lo < hi) { int mid = (lo + hi) >> 1; if (batch[mid] < g + 1) lo = mid + 1; else hi = mid; }
        s_cnt = lo - st;
    }
    __syncthreads();
    float dot = 0.f;
    for (int k = 0; k < 256; k += 4) {
        float4 pk = *(const float4*)(s_pool + k);
        dot += pk.x * W2[(k + 0) * 256 + c];
        dot += pk.y * W2[(k + 1) * 256 + c];
        dot += pk.z * W2[(k + 2) * 256 + c];
        dot += pk.w * W2[(k + 3) * 256 + c];
    }
    float r = 0.f;
    int cntg = s_cnt;
    if (cntg > 0) {
        float mean = dot / (float)cntg + b[c];
        r = (mean - m[c]) * rsqrtf(v[c] + BN_EPSF) * gw[c] + be[c];
    }
    out[g * 256 + c] = r;
}

// ---------------- launch ----------------

static inline size_t align_up(size_t x, size_t a) { return (x + a - 1) & ~(a - 1); }

extern "C" void kernel_launch(void* const* d_in, const int* in_sizes, int n_in,
                              void* d_out, int out_size, void* d_ws, size_t ws_size,
                              hipStream_t stream) {
    const float* x = (const float*)d_in[0];
    const int* edge_index = (const int*)d_in[1];
    const int* batch = (const int*)d_in[2];

    const int N = in_sizes[2];          // 50000 (< 2^16, required by u32/u16 packing)
    const int E = in_sizes[1] / 2;      // 1600000
    const int NCH = (N + CH_J - 1) / CH_J;   // pooled-GEMM chunks (98)
    const int N_pad = NCH * CH_J;            // 50176 = PBKT*128

    const int* e_src = edge_index;
    const int* e_dst = edge_index + E;

    const float* W[3]; const float* bP[3]; const float* gP[3];
    const float* beP[3]; const float* mP[3]; const float* vP[3];
    for (int i = 0; i < 3; i++) {
        W[i]  = (const float*)d_in[3 + 6 * i + 0];
        bP[i] = (const float*)d_in[3 + 6 * i + 1];
        gP[i] = (const float*)d_in[3 + 6 * i + 2];
        beP[i]= (const float*)d_in[3 + 6 * i + 3];
        mP[i] = (const float*)d_in[3 + 6 * i + 4];
        vP[i] = (const float*)d_in[3 + 6 * i + 5];
    }

    // workspace carve-up
    char* ws = (char*)d_ws;
    size_t off = 0;
    auto carve = [&](size_t bytes) { void* p = ws + off; off = align_up(off + bytes, 256); return p; };
    int*   curD     = (int*)  carve((size_t)2 * PBKT * 4);   // bucket cursors, one memset
    int*   curS     = curD + PBKT;
    int*   cnt      = (int*)  carve((size_t)N * 4);
    float* dinv     = (float*)carve((size_t)N * 4);
    float2* pack    = (float2*)carve((size_t)N * 8);
    float4* x4      = (float4*)carve((size_t)N * 16);
    unsigned* partD = (unsigned*)carve((size_t)PBKT * PCAP * 4);  // 7.2 MB (packed u32)
    unsigned* partS = (unsigned*)carve((size_t)PBKT * PCAP * 4);  // 7.2 MB
    unsigned short* ell_in = (unsigned short*)carve((size_t)N * ELLW * 2);  // 9.6 MB (u16)
    unsigned short* bufA = (unsigned short*)carve((size_t)N_pad * NFEAT * 2);  // A1 bf16
    unsigned char*  bufA0 = (unsigned char*)carve((size_t)N_pad * NFEAT);   // fp8 A0 (12.8 MB)
    unsigned char*  bufY = (unsigned char*)carve((size_t)N_pad * NFEAT);    // fp8 Y (12.8 MB)
    unsigned char*  Wt_hi = (unsigned char*)carve((size_t)NFEAT * NFEAT);   // fp8 W1 hi
    unsigned char*  Wt_lo = (unsigned char*)carve((size_t)NFEAT * NFEAT);   // fp8 W1 lo
    unsigned short* ct_hi = (unsigned short*)carve((size_t)N_pad * 64 * 2);
    unsigned short* ct_lo = (unsigned short*)carve((size_t)N_pad * 64 * 2);
    float* partials = (float*)carve((size_t)NCH * 64 * 256 * 4);     // 6.4 MB
    float* pooled   = (float*)carve((size_t)64 * 256 * 4);
    (void)ws_size;

    hipMemsetAsync(curD, 0, (size_t)2 * PBKT * 4, stream);

    const int BS = 256;
    // phase 1: partition edges (packed u32 entries; LDS-cached chunk)
    k_part<<<(E + PEDG - 1) / PEDG, BS, 0, stream>>>(e_src, e_dst, curD, curS, partD, partS, E);
    // merged prep: W1 -> fp8 hi/lo (x8) + x float4 repack
    k_prep<<<256 + (N + BS - 1) / BS, BS, 0, stream>>>(W[1], Wt_hi, Wt_lo, x, x4, N);
    // phase 2: ELL rows in LDS -> coalesced u16 write; cnt/dinv/pack fall out
    k_buildIn<<<PBKT, BS, 0, stream>>>(partD, curD, batch, ell_in, cnt, dinv, pack, N);
    // phase 3: Ct rows in LDS -> transposed bf16 hi/lo directly
    k_buildCt<<<PBKT, BS, 0, stream>>>(partS, curS, pack, ct_hi, ct_lo, N, N_pad);

    // layer 0 fused: gather-aggregate (float4 x) + 3->256 matmul + BN + ReLU -> fp8 A0 (+pad zero)
    k_l0<<<N_pad / 4, BS, 0, stream>>>(x4, ell_in, cnt, dinv, W[0],
                                       bP[0], gP[0], beP[0], mP[0], vP[0], bufA0, N);

    dim3 mmGrid((N + 127) / 128, 2);
    // layer 1: Y = A0@W1 via fp8 MFMA (hi/lo W1, Y x8 fp8) -> propagate -> BN + ReLU -> bf16 A1
    k_mm_mfma<<<mmGrid, 256, 0, stream>>>(bufA0, Wt_hi, Wt_lo, bufY);
    k_agg256b<true><<<N_pad, 64, 0, stream>>>(bufY, ell_in, cnt, dinv,
                                              bP[1], gP[1], beP[1], mP[1], vP[1], bufA, N);

    // layer 2 + pool (W2 folded out): P = per-chunk Ct^T @ A1 via MFMA; out = BN((P@W2)/n + b2)
    dim3 cgGrid(NCH, 4);
    k_cgemm<<<cgGrid, 256, 0, stream>>>(bufA, ct_hi, ct_lo, partials, N_pad);
    k_redP<<<256, 64, 0, stream>>>(partials, pooled, NCH);
    k_out<<<64, 256, 0, stream>>>(pooled, W[2], batch, bP[2], gP[2], beP[2], mP[2], vP[2],
                                  (float*)d_out, N);
}